// Round 8
// baseline (348.803 us; speedup 1.0000x reference)
//
#include <hip/hip_runtime.h>

#define NN 50000
#define NE 800000
#define NB 782    // ceil(NN/64) buckets of 64 dst-nodes
#define CAP 1536  // per-bucket edge capacity (avg 1023, sigma 32 -> +16 sigma)

// ---------------- bf16 helpers (bits-level, RNE) ----------------

__device__ __forceinline__ unsigned short f2bf(float f) {
    union { float f; unsigned u; } v; v.f = f;
    unsigned u = v.u;
    return (unsigned short)((u + 0x7fffu + ((u >> 16) & 1u)) >> 16);
}
__device__ __forceinline__ float bfu_lo(unsigned p) {
    union { unsigned u; float f; } v; v.u = p << 16; return v.f;
}
__device__ __forceinline__ float bfu_hi(unsigned p) {
    union { unsigned u; float f; } v; v.u = p & 0xffff0000u; return v.f;
}

typedef __bf16 bf16x8 __attribute__((ext_vector_type(8)));
typedef float f32x4 __attribute__((ext_vector_type(4)));
union U16 { uint4 u; bf16x8 v; };

// ---------------- prep: binscatter + x->bf16 cast + W pack, one launch -------------------
// Disjoint blockIdx ranges; the three jobs are mutually independent.

#define BS_BLOCKS ((NE + 8191) / 8192)              // 98
#define CAST_BLOCKS ((NN * 128 / 4 + 255) / 256)    // 6250
#define PACK_BLOCKS ((24 * 8 * 64) / 256)           // 48

__device__ void binscatter_job(const int* __restrict__ src, const int* __restrict__ dst,
                               int* __restrict__ bcnt, unsigned* __restrict__ ebuf, int blk) {
    __shared__ int hist[NB];
    __shared__ int base[NB];
    const int BE = 8192;
    int tid = threadIdx.x;
    int e0 = blk * BE;
    for (int i = tid; i < NB; i += 256) hist[i] = 0;
    __syncthreads();
    for (int i = tid; i < BE; i += 256) {
        int e = e0 + i;
        if (e < NE) atomicAdd(&hist[dst[e] >> 6], 1);
    }
    __syncthreads();
    for (int i = tid; i < NB; i += 256) {
        int c = hist[i];
        base[i] = c ? atomicAdd(&bcnt[i], c) : 0;  // reserve contiguous run
        hist[i] = 0;                                // reuse as cursor
    }
    __syncthreads();
    for (int i = tid; i < BE; i += 256) {
        int e = e0 + i;
        if (e < NE) {
            int d = dst[e], b = d >> 6;
            int slot = base[b] + atomicAdd(&hist[b], 1);
            if (slot < CAP)
                ebuf[(size_t)b * CAP + slot] = (unsigned)src[e] | ((unsigned)(d & 63) << 16);
        }
    }
}

template <int N>
__device__ __forceinline__ void pack_one(const float* __restrict__ Wl,
                                         const float* __restrict__ Wr,
                                         unsigned short* __restrict__ Wp, int t) {
    // chunk c = nt*8+ks; lane holds B[k=ks*32+(lane>>4)*8+j][n=nt*16+(lane&15)], j=0..7
    int lane = t & 63, c = t >> 6;
    int ks = c & 7, nt = c >> 3;
    int n = nt * 16 + (lane & 15);
    int kq = ks * 32 + (lane >> 4) * 8;
    unsigned short tmp[8];
#pragma unroll
    for (int j = 0; j < 8; j++) {
        int k = kq + j;
        float w = (k < 128) ? Wl[(size_t)k * N + n] : Wr[(size_t)(k - 128) * N + n];
        tmp[j] = f2bf(w);
    }
    ((ushort4*)Wp)[(size_t)c * 128 + lane * 2 + 0] = make_ushort4(tmp[0], tmp[1], tmp[2], tmp[3]);
    ((ushort4*)Wp)[(size_t)c * 128 + lane * 2 + 1] = make_ushort4(tmp[4], tmp[5], tmp[6], tmp[7]);
}

__global__ __launch_bounds__(256) void prep_kernel(
    const int* __restrict__ src, const int* __restrict__ dst,
    int* __restrict__ bcnt, unsigned* __restrict__ ebuf,
    const float* __restrict__ x, unsigned short* __restrict__ x_bf,
    const float* __restrict__ W1l, const float* __restrict__ W1r, unsigned short* __restrict__ W1p,
    const float* __restrict__ W2l, const float* __restrict__ W2r, unsigned short* __restrict__ W2p) {
    int b = blockIdx.x;
    if (b < BS_BLOCKS) {
        binscatter_job(src, dst, bcnt, ebuf, b);
    } else if (b < BS_BLOCKS + CAST_BLOCKS) {
        int i = (b - BS_BLOCKS) * 256 + threadIdx.x;
        if (i < NN * 128 / 4) {
            float4 f = ((const float4*)x)[i];
            ((ushort4*)x_bf)[i] = make_ushort4(f2bf(f.x), f2bf(f.y), f2bf(f.z), f2bf(f.w));
        }
    } else {
        int t = (b - BS_BLOCKS - CAST_BLOCKS) * 256 + threadIdx.x;
        if (t < 8 * 8 * 64) pack_one<128>(W1l, W1r, W1p, t);
        else if (t < 24 * 8 * 64) pack_one<256>(W2l, W2r, W2p, t - 8 * 8 * 64);
    }
}

// ---------------- csr: one block per bucket (prefix over bcnt folded in) -------------------

__global__ __launch_bounds__(256) void csr_kernel(const int* __restrict__ bcnt,
                                                  const unsigned* __restrict__ ebuf,
                                                  int* __restrict__ rowptr,
                                                  int* __restrict__ col) {
    __shared__ int red[256];
    __shared__ int deg[64];
    __shared__ int cur[64];
    __shared__ int cbase_s;
    int b = blockIdx.x, tid = threadIdx.x;
    int s = 0;
    for (int i = tid; i < b; i += 256) s += bcnt[i];
    red[tid] = s;
    if (tid < 64) deg[tid] = 0;
    __syncthreads();
    for (int off = 128; off; off >>= 1) {
        if (tid < off) red[tid] += red[tid + off];
        __syncthreads();
    }
    if (tid == 0) cbase_s = red[0];
    __syncthreads();
    int cnt = bcnt[b], cbase = cbase_s;
    if (cnt > CAP) cnt = CAP;
    const unsigned* eb = ebuf + (size_t)b * CAP;
    for (int i = tid; i < cnt; i += 256) atomicAdd(&deg[(eb[i] >> 16) & 63], 1);
    __syncthreads();
    if (tid == 0) {
        int run = 0;
        for (int j = 0; j < 64; j++) { cur[j] = run; run += deg[j]; }
    }
    __syncthreads();
    int node = b * 64 + tid;
    if (tid < 64 && node < NN) rowptr[node] = cbase + cur[tid];
    if (b == NB - 1 && tid == 0) rowptr[NN] = NE;
    __syncthreads();
    for (int i = tid; i < cnt; i += 256) {
        unsigned e = eb[i];
        int pos = atomicAdd(&cur[(e >> 16) & 63], 1);
        col[cbase + pos] = (int)(e & 0xffffu);
    }
}

// ---------------- fused aggregate + MFMA GEMM + epilogue per layer -------------------------
// Block = 64 rows, 4 waves. Phase 1: wave w mean-aggregates its own 16 nodes (4-neighbor
// uint4-vectorized gather; lane-group g targets neighbor i+g), result -> LDS tile (row pad
// 17 uint4 -> <=2-way bank alias = free). Phase 2: A0-frags from LDS (the transpose),
// A1-frags from feat rows (global, 16B coalesced), 8 MFMAs/col-tile, fused
// bias+sigmoid+L2 (+log_softmax). No agg round-trip through global memory.

template <int N, bool FINAL>
__global__ __launch_bounds__(256) void fused_layer_kernel(
    const int* __restrict__ rowptr, const int* __restrict__ col,
    const unsigned short* __restrict__ feat,  // prev-layer features [NN][128] bf16
    const unsigned short* __restrict__ Wp, const float* __restrict__ bias,
    void* __restrict__ outp) {
    const int NT = N / 16;
    __shared__ uint4 sA[64 * 17];
    int tid = threadIdx.x, wave = tid >> 6, lane = tid & 63;
    int g = lane >> 4, c16 = lane & 15;
    const uint4* feat4 = (const uint4*)feat;

    // phase 1: aggregate this wave's 16 rows
    for (int t = 0; t < 16; t++) {
        int node = blockIdx.x * 64 + wave * 16 + t;
        if (node >= NN) break;
        int beg = rowptr[node], end = rowptr[node + 1];
        float ac[8];
#pragma unroll
        for (int j = 0; j < 8; j++) ac[j] = 0.f;
        for (int i = beg; i < end; i += 4) {
            int idx = i + g;
            if (idx < end) {
                int sn = col[idx];
                uint4 v = feat4[(size_t)sn * 16 + c16];
                ac[0] += bfu_lo(v.x); ac[1] += bfu_hi(v.x);
                ac[2] += bfu_lo(v.y); ac[3] += bfu_hi(v.y);
                ac[4] += bfu_lo(v.z); ac[5] += bfu_hi(v.z);
                ac[6] += bfu_lo(v.w); ac[7] += bfu_hi(v.w);
            }
        }
#pragma unroll
        for (int j = 0; j < 8; j++) {
            ac[j] += __shfl_xor(ac[j], 16);
            ac[j] += __shfl_xor(ac[j], 32);
        }
        if (g == 0) {
            float inv = (end > beg) ? 1.0f / (float)(end - beg) : 0.0f;
            uint4 o;
            o.x = (unsigned)f2bf(ac[0] * inv) | ((unsigned)f2bf(ac[1] * inv) << 16);
            o.y = (unsigned)f2bf(ac[2] * inv) | ((unsigned)f2bf(ac[3] * inv) << 16);
            o.z = (unsigned)f2bf(ac[4] * inv) | ((unsigned)f2bf(ac[5] * inv) << 16);
            o.w = (unsigned)f2bf(ac[6] * inv) | ((unsigned)f2bf(ac[7] * inv) << 16);
            sA[(wave * 16 + t) * 17 + c16] = o;
        }
    }
    __syncthreads();

    // phase 2: GEMM. quad = lane>>4, cl = lane&15; wave owns rows m_base..+15.
    int quad = g, cl = c16;
    int m_base = blockIdx.x * 64 + wave * 16;
    int row = m_base + cl;
    int row_ld = row < NN ? row : NN - 1;

    bf16x8 a[8];
#pragma unroll
    for (int ks = 0; ks < 4; ks++) {  // A0 = agg, from LDS (k = ks*32 + quad*8 .. +8)
        U16 u; u.u = sA[(wave * 16 + cl) * 17 + ks * 4 + quad];
        a[ks] = u.v;
    }
    const uint4* a1p = (const uint4*)(feat + (size_t)row_ld * 128 + quad * 8);
#pragma unroll
    for (int ks = 0; ks < 4; ks++) { U16 u; u.u = a1p[ks * 4]; a[4 + ks] = u.v; }

    f32x4 acc[NT];
#pragma unroll
    for (int nt = 0; nt < NT; nt++) acc[nt] = (f32x4){0.f, 0.f, 0.f, 0.f};

    const uint4* wp = (const uint4*)Wp;  // chunk c: wp[c*64 + lane]
#pragma unroll
    for (int nt = 0; nt < NT; nt++) {
#pragma unroll
        for (int ks = 0; ks < 8; ks++) {
            U16 u; u.u = wp[(size_t)(nt * 8 + ks) * 64 + lane];
            acc[nt] = __builtin_amdgcn_mfma_f32_16x16x32_bf16(a[ks], u.v, acc[nt], 0, 0, 0);
        }
    }

    // epilogue: bias + sigmoid + row L2-norm (row reductions: shfl_xor width-16 in quad)
    float ssq[4] = {0.f, 0.f, 0.f, 0.f};
#pragma unroll
    for (int nt = 0; nt < NT; nt++) {
        float bv = bias[nt * 16 + cl];
#pragma unroll
        for (int r = 0; r < 4; r++) {
            float z = acc[nt][r] + bv;
            float s = 1.0f / (1.0f + __expf(-z));
            acc[nt][r] = s;
            ssq[r] += s * s;
        }
    }
#pragma unroll
    for (int r = 0; r < 4; r++) {
#pragma unroll
        for (int off = 1; off < 16; off <<= 1) ssq[r] += __shfl_xor(ssq[r], off, 16);
        float sc = 1.0f / fmaxf(sqrtf(ssq[r]), 1e-12f);
#pragma unroll
        for (int nt = 0; nt < NT; nt++) acc[nt][r] *= sc;
    }

    if (FINAL) {  // log_softmax per row, fp32 out
#pragma unroll
        for (int r = 0; r < 4; r++) {
            float mx = -1e30f;
#pragma unroll
            for (int nt = 0; nt < NT; nt++) mx = fmaxf(mx, acc[nt][r]);
#pragma unroll
            for (int off = 1; off < 16; off <<= 1) mx = fmaxf(mx, __shfl_xor(mx, off, 16));
            float se = 0.f;
#pragma unroll
            for (int nt = 0; nt < NT; nt++) se += __expf(acc[nt][r] - mx);
#pragma unroll
            for (int off = 1; off < 16; off <<= 1) se += __shfl_xor(se, off, 16);
            float lse = mx + __logf(se);
#pragma unroll
            for (int nt = 0; nt < NT; nt++) acc[nt][r] -= lse;
        }
        float* op = (float*)outp;
#pragma unroll
        for (int r = 0; r < 4; r++) {
            int m = m_base + quad * 4 + r;
            if (m < NN) {
#pragma unroll
                for (int nt = 0; nt < NT; nt++) op[(size_t)m * N + nt * 16 + cl] = acc[nt][r];
            }
        }
    } else {  // bf16 out (feeds layer-2 gather + A1)
        unsigned short* op = (unsigned short*)outp;
#pragma unroll
        for (int r = 0; r < 4; r++) {
            int m = m_base + quad * 4 + r;
            if (m < NN) {
#pragma unroll
                for (int nt = 0; nt < NT; nt++)
                    op[(size_t)m * N + nt * 16 + cl] = f2bf(acc[nt][r]);
            }
        }
    }
}

// ---------------- launcher (5 graph nodes) ----------------

extern "C" void kernel_launch(void* const* d_in, const int* in_sizes, int n_in,
                              void* d_out, int out_size, void* d_ws, size_t ws_size,
                              hipStream_t stream) {
    const float* x   = (const float*)d_in[0];
    const int*   ei  = (const int*)d_in[1];
    const float* W1l = (const float*)d_in[2];
    const float* W1r = (const float*)d_in[3];
    const float* b1  = (const float*)d_in[4];
    const float* W2l = (const float*)d_in[5];
    const float* W2r = (const float*)d_in[6];
    const float* b2  = (const float*)d_in[7];
    float* out = (float*)d_out;

    const int* src = ei;
    const int* dst = ei + NE;

    char* ws = (char*)d_ws;
    size_t off = 0;
    auto alloc = [&](size_t bytes) -> void* {
        void* p = ws + off;
        off += (bytes + 255) / 256 * 256;
        return p;
    };
    int* rowptr     = (int*)alloc((size_t)(NN + 1) * 4);
    int* col        = (int*)alloc((size_t)NE * 4);
    int* bcnt       = (int*)alloc((size_t)NB * 4);
    unsigned* ebuf  = (unsigned*)alloc((size_t)NB * CAP * 4);  // 4.8MB
    unsigned short* x_bf  = (unsigned short*)alloc((size_t)NN * 128 * 2);
    unsigned short* h1_bf = (unsigned short*)alloc((size_t)NN * 128 * 2);
    unsigned short* W1p   = (unsigned short*)alloc((size_t)8 * 8 * 64 * 8 * 2);    // 64KB
    unsigned short* W2p   = (unsigned short*)alloc((size_t)16 * 8 * 64 * 8 * 2);   // 128KB

    hipMemsetAsync(bcnt, 0, (size_t)NB * 4, stream);
    prep_kernel<<<BS_BLOCKS + CAST_BLOCKS + PACK_BLOCKS, 256, 0, stream>>>(
        src, dst, bcnt, ebuf, x, x_bf, W1l, W1r, W1p, W2l, W2r, W2p);
    csr_kernel<<<NB, 256, 0, stream>>>(bcnt, ebuf, rowptr, col);
    fused_layer_kernel<128, false><<<(NN + 63) / 64, 256, 0, stream>>>(rowptr, col, x_bf, W1p,
                                                                       b1, h1_bf);
    fused_layer_kernel<256, true><<<(NN + 63) / 64, 256, 0, stream>>>(rowptr, col, h1_bf, W2p,
                                                                      b2, out);
}

// Round 9
// 331.787 us; speedup vs baseline: 1.0513x; 1.0513x over previous
//
#include <hip/hip_runtime.h>

#define NN 50000
#define NE 800000
#define NB 782    // ceil(NN/64) buckets of 64 dst-nodes
#define CAP 1536  // per-bucket edge capacity (avg 1023, sigma 32 -> +16 sigma)

// ---------------- bf16 helpers (bits-level, RNE) ----------------

__device__ __forceinline__ unsigned short f2bf(float f) {
    union { float f; unsigned u; } v; v.f = f;
    unsigned u = v.u;
    return (unsigned short)((u + 0x7fffu + ((u >> 16) & 1u)) >> 16);
}
__device__ __forceinline__ float bfu_lo(unsigned p) {
    union { unsigned u; float f; } v; v.u = p << 16; return v.f;
}
__device__ __forceinline__ float bfu_hi(unsigned p) {
    union { unsigned u; float f; } v; v.u = p & 0xffff0000u; return v.f;
}

typedef __bf16 bf16x8 __attribute__((ext_vector_type(8)));
typedef float f32x4 __attribute__((ext_vector_type(4)));
union U16 { uint4 u; bf16x8 v; };

// ---------------- prep: binscatter + x->bf16 cast + W pack, one launch -------------------

#define BS_BLOCKS ((NE + 8191) / 8192)              // 98
#define CAST_BLOCKS ((NN * 128 / 4 + 255) / 256)    // 6250
#define PACK_BLOCKS ((24 * 8 * 64) / 256)           // 48

__device__ void binscatter_job(const int* __restrict__ src, const int* __restrict__ dst,
                               int* __restrict__ bcnt, unsigned* __restrict__ ebuf, int blk) {
    __shared__ int hist[NB];
    __shared__ int base[NB];
    const int BE = 8192;
    int tid = threadIdx.x;
    int e0 = blk * BE;
    for (int i = tid; i < NB; i += 256) hist[i] = 0;
    __syncthreads();
    for (int i = tid; i < BE; i += 256) {
        int e = e0 + i;
        if (e < NE) atomicAdd(&hist[dst[e] >> 6], 1);
    }
    __syncthreads();
    for (int i = tid; i < NB; i += 256) {
        int c = hist[i];
        base[i] = c ? atomicAdd(&bcnt[i], c) : 0;  // reserve contiguous run
        hist[i] = 0;                                // reuse as cursor
    }
    __syncthreads();
    for (int i = tid; i < BE; i += 256) {
        int e = e0 + i;
        if (e < NE) {
            int d = dst[e], b = d >> 6;
            int slot = base[b] + atomicAdd(&hist[b], 1);
            if (slot < CAP)
                ebuf[(size_t)b * CAP + slot] = (unsigned)src[e] | ((unsigned)(d & 63) << 16);
        }
    }
}

template <int N>
__device__ __forceinline__ void pack_one(const float* __restrict__ Wl,
                                         const float* __restrict__ Wr,
                                         unsigned short* __restrict__ Wp, int t) {
    // chunk c = nt*8+ks; lane holds B[k=ks*32+(lane>>4)*8+j][n=nt*16+(lane&15)], j=0..7
    int lane = t & 63, c = t >> 6;
    int ks = c & 7, nt = c >> 3;
    int n = nt * 16 + (lane & 15);
    int kq = ks * 32 + (lane >> 4) * 8;
    unsigned short tmp[8];
#pragma unroll
    for (int j = 0; j < 8; j++) {
        int k = kq + j;
        float w = (k < 128) ? Wl[(size_t)k * N + n] : Wr[(size_t)(k - 128) * N + n];
        tmp[j] = f2bf(w);
    }
    ((ushort4*)Wp)[(size_t)c * 128 + lane * 2 + 0] = make_ushort4(tmp[0], tmp[1], tmp[2], tmp[3]);
    ((ushort4*)Wp)[(size_t)c * 128 + lane * 2 + 1] = make_ushort4(tmp[4], tmp[5], tmp[6], tmp[7]);
}

__global__ __launch_bounds__(256) void prep_kernel(
    const int* __restrict__ src, const int* __restrict__ dst,
    int* __restrict__ bcnt, unsigned* __restrict__ ebuf,
    const float* __restrict__ x, unsigned short* __restrict__ x_bf,
    const float* __restrict__ W1l, const float* __restrict__ W1r, unsigned short* __restrict__ W1p,
    const float* __restrict__ W2l, const float* __restrict__ W2r, unsigned short* __restrict__ W2p) {
    int b = blockIdx.x;
    if (b < BS_BLOCKS) {
        binscatter_job(src, dst, bcnt, ebuf, b);
    } else if (b < BS_BLOCKS + CAST_BLOCKS) {
        int i = (b - BS_BLOCKS) * 256 + threadIdx.x;
        if (i < NN * 128 / 4) {
            float4 f = ((const float4*)x)[i];
            ((ushort4*)x_bf)[i] = make_ushort4(f2bf(f.x), f2bf(f.y), f2bf(f.z), f2bf(f.w));
        }
    } else {
        int t = (b - BS_BLOCKS - CAST_BLOCKS) * 256 + threadIdx.x;
        if (t < 8 * 8 * 64) pack_one<128>(W1l, W1r, W1p, t);
        else if (t < 24 * 8 * 64) pack_one<256>(W2l, W2r, W2p, t - 8 * 8 * 64);
    }
}

// ---------------- csr: one block per bucket (prefix over bcnt folded in) -------------------

__global__ __launch_bounds__(256) void csr_kernel(const int* __restrict__ bcnt,
                                                  const unsigned* __restrict__ ebuf,
                                                  int* __restrict__ rowptr,
                                                  int* __restrict__ col) {
    __shared__ int red[256];
    __shared__ int deg[64];
    __shared__ int cur[64];
    __shared__ int cbase_s;
    int b = blockIdx.x, tid = threadIdx.x;
    int s = 0;
    for (int i = tid; i < b; i += 256) s += bcnt[i];
    red[tid] = s;
    if (tid < 64) deg[tid] = 0;
    __syncthreads();
    for (int off = 128; off; off >>= 1) {
        if (tid < off) red[tid] += red[tid + off];
        __syncthreads();
    }
    if (tid == 0) cbase_s = red[0];
    __syncthreads();
    int cnt = bcnt[b], cbase = cbase_s;
    if (cnt > CAP) cnt = CAP;
    const unsigned* eb = ebuf + (size_t)b * CAP;
    for (int i = tid; i < cnt; i += 256) atomicAdd(&deg[(eb[i] >> 16) & 63], 1);
    __syncthreads();
    if (tid == 0) {
        int run = 0;
        for (int j = 0; j < 64; j++) { cur[j] = run; run += deg[j]; }
    }
    __syncthreads();
    int node = b * 64 + tid;
    if (tid < 64 && node < NN) rowptr[node] = cbase + cur[tid];
    if (b == NB - 1 && tid == 0) rowptr[NN] = NE;
    __syncthreads();
    for (int i = tid; i < cnt; i += 256) {
        unsigned e = eb[i];
        int pos = atomicAdd(&cur[(e >> 16) & 63], 1);
        col[cbase + pos] = (int)(e & 0xffffu);
    }
}

// ---------------- chunked L2-resident mean aggregation -------------------------------------
// Feature row (256B) split into 4 x 64B chunks; chunk is the SLOWEST grid index, so all
// in-flight blocks touch a 3.2MB table slice -> fits 4MiB per-XCD L2, gathers become L2
// hits. Wave handles one (node, chunk): lane = neighbor (lane>>2) x sub-16B (lane&3) ->
// 16 neighbors x 64B in flight per load instr; typical deg=16 -> ONE iteration.
// Neighbor reduction: shfl_xor over lane bits 2..5; lanes 0..3 write the 64B output chunk.

__global__ void aggregate_bf_kernel(const int* __restrict__ rowptr, const int* __restrict__ col,
                                    const uint4* __restrict__ feat4,  // [NN][16] 16B units
                                    uint4* __restrict__ out4) {
    int c = blockIdx.x / 12500;                                // chunk 0..3 (slowest)
    int node = (blockIdx.x % 12500) * 4 + (threadIdx.x >> 6);  // 4 waves/block
    int lane = threadIdx.x & 63;
    if (node >= NN) return;
    int beg = rowptr[node], end = rowptr[node + 1];
    int nb = lane >> 2, sub = lane & 3;
    float acc[8];
#pragma unroll
    for (int j = 0; j < 8; j++) acc[j] = 0.f;
    for (int i = beg; i < end; i += 16) {
        int idx = i + nb;
        if (idx < end) {  // exec-masked: no wasted loads
            int s = col[idx];
            uint4 v = feat4[(size_t)s * 16 + c * 4 + sub];
            acc[0] += bfu_lo(v.x); acc[1] += bfu_hi(v.x);
            acc[2] += bfu_lo(v.y); acc[3] += bfu_hi(v.y);
            acc[4] += bfu_lo(v.z); acc[5] += bfu_hi(v.z);
            acc[6] += bfu_lo(v.w); acc[7] += bfu_hi(v.w);
        }
    }
#pragma unroll
    for (int j = 0; j < 8; j++) {
        acc[j] += __shfl_xor(acc[j], 4);
        acc[j] += __shfl_xor(acc[j], 8);
        acc[j] += __shfl_xor(acc[j], 16);
        acc[j] += __shfl_xor(acc[j], 32);
    }
    if (lane < 4) {  // lane == sub here; write full 64B line
        float inv = (end > beg) ? 1.0f / (float)(end - beg) : 0.0f;
        uint4 o;
        o.x = (unsigned)f2bf(acc[0] * inv) | ((unsigned)f2bf(acc[1] * inv) << 16);
        o.y = (unsigned)f2bf(acc[2] * inv) | ((unsigned)f2bf(acc[3] * inv) << 16);
        o.z = (unsigned)f2bf(acc[4] * inv) | ((unsigned)f2bf(acc[5] * inv) << 16);
        o.w = (unsigned)f2bf(acc[6] * inv) | ((unsigned)f2bf(acc[7] * inv) << 16);
        out4[(size_t)node * 16 + c * 4 + lane] = o;
    }
}

// ---------------- MFMA GEMM + fused epilogue (no LDS, no barriers) — R7-proven -------------
// C[M,N] = [A0|A1](bf16) @ Wp + bias; sigmoid + row-L2 (+ log_softmax if FINAL).
// 256 thr = 4 waves; wave owns 16 rows x all N cols. A-frags: row-major 16B loads
// (A[m=lane&15][k=quad*8+j]); K=256 resident in 32 VGPRs. B-frags: 1KB coalesced chunks
// from L2-resident Wp. C/D: row=quad*4+reg, col=lane&15 -> shfl_xor width-16 reductions.

template <int N, bool FINAL>
__global__ __launch_bounds__(256) void gemm_mfma_kernel(
    const unsigned short* __restrict__ A0, const unsigned short* __restrict__ A1,
    const unsigned short* __restrict__ Wp, const float* __restrict__ bias,
    void* __restrict__ outp, int M) {
    const int NT = N / 16;
    int tid = threadIdx.x, wave = tid >> 6, lane = tid & 63;
    int quad = lane >> 4, col = lane & 15;
    int m_base = blockIdx.x * 64 + wave * 16;
    int row = m_base + col;
    int row_ld = row < M ? row : M - 1;

    bf16x8 a[8];
    const uint4* a0p = (const uint4*)(A0 + (size_t)row_ld * 128 + quad * 8);
    const uint4* a1p = (const uint4*)(A1 + (size_t)row_ld * 128 + quad * 8);
#pragma unroll
    for (int ks = 0; ks < 4; ks++) { U16 u; u.u = a0p[ks * 4]; a[ks] = u.v; }
#pragma unroll
    for (int ks = 0; ks < 4; ks++) { U16 u; u.u = a1p[ks * 4]; a[4 + ks] = u.v; }

    f32x4 acc[NT];
#pragma unroll
    for (int nt = 0; nt < NT; nt++) acc[nt] = (f32x4){0.f, 0.f, 0.f, 0.f};

    const uint4* wp = (const uint4*)Wp;  // chunk c: wp[c*64 + lane]
#pragma unroll
    for (int nt = 0; nt < NT; nt++) {
#pragma unroll
        for (int ks = 0; ks < 8; ks++) {
            U16 u; u.u = wp[(size_t)(nt * 8 + ks) * 64 + lane];
            acc[nt] = __builtin_amdgcn_mfma_f32_16x16x32_bf16(a[ks], u.v, acc[nt], 0, 0, 0);
        }
    }

    float ssq[4] = {0.f, 0.f, 0.f, 0.f};
#pragma unroll
    for (int nt = 0; nt < NT; nt++) {
        float bv = bias[nt * 16 + col];
#pragma unroll
        for (int r = 0; r < 4; r++) {
            float z = acc[nt][r] + bv;
            float s = 1.0f / (1.0f + __expf(-z));
            acc[nt][r] = s;
            ssq[r] += s * s;
        }
    }
#pragma unroll
    for (int r = 0; r < 4; r++) {
#pragma unroll
        for (int off = 1; off < 16; off <<= 1) ssq[r] += __shfl_xor(ssq[r], off, 16);
        float sc = 1.0f / fmaxf(sqrtf(ssq[r]), 1e-12f);
#pragma unroll
        for (int nt = 0; nt < NT; nt++) acc[nt][r] *= sc;
    }

    if (FINAL) {
#pragma unroll
        for (int r = 0; r < 4; r++) {
            float mx = -1e30f;
#pragma unroll
            for (int nt = 0; nt < NT; nt++) mx = fmaxf(mx, acc[nt][r]);
#pragma unroll
            for (int off = 1; off < 16; off <<= 1) mx = fmaxf(mx, __shfl_xor(mx, off, 16));
            float se = 0.f;
#pragma unroll
            for (int nt = 0; nt < NT; nt++) se += __expf(acc[nt][r] - mx);
#pragma unroll
            for (int off = 1; off < 16; off <<= 1) se += __shfl_xor(se, off, 16);
            float lse = mx + __logf(se);
#pragma unroll
            for (int nt = 0; nt < NT; nt++) acc[nt][r] -= lse;
        }
        float* op = (float*)outp;
#pragma unroll
        for (int r = 0; r < 4; r++) {
            int m = m_base + quad * 4 + r;
            if (m < M) {
#pragma unroll
                for (int nt = 0; nt < NT; nt++) op[(size_t)m * N + nt * 16 + col] = acc[nt][r];
            }
        }
    } else {
        unsigned short* op = (unsigned short*)outp;
#pragma unroll
        for (int r = 0; r < 4; r++) {
            int m = m_base + quad * 4 + r;
            if (m < M) {
#pragma unroll
                for (int nt = 0; nt < NT; nt++)
                    op[(size_t)m * N + nt * 16 + col] = f2bf(acc[nt][r]);
            }
        }
    }
}

// ---------------- launcher ----------------

extern "C" void kernel_launch(void* const* d_in, const int* in_sizes, int n_in,
                              void* d_out, int out_size, void* d_ws, size_t ws_size,
                              hipStream_t stream) {
    const float* x   = (const float*)d_in[0];
    const int*   ei  = (const int*)d_in[1];
    const float* W1l = (const float*)d_in[2];
    const float* W1r = (const float*)d_in[3];
    const float* b1  = (const float*)d_in[4];
    const float* W2l = (const float*)d_in[5];
    const float* W2r = (const float*)d_in[6];
    const float* b2  = (const float*)d_in[7];
    float* out = (float*)d_out;

    const int* src = ei;
    const int* dst = ei + NE;

    char* ws = (char*)d_ws;
    size_t off = 0;
    auto alloc = [&](size_t bytes) -> void* {
        void* p = ws + off;
        off += (bytes + 255) / 256 * 256;
        return p;
    };
    int* rowptr     = (int*)alloc((size_t)(NN + 1) * 4);
    int* col        = (int*)alloc((size_t)NE * 4);
    int* bcnt       = (int*)alloc((size_t)NB * 4);
    unsigned* ebuf  = (unsigned*)alloc((size_t)NB * CAP * 4);  // 4.8MB
    unsigned short* x_bf   = (unsigned short*)alloc((size_t)NN * 128 * 2);
    unsigned short* agg_bf = (unsigned short*)alloc((size_t)NN * 128 * 2);
    unsigned short* h1_bf  = (unsigned short*)alloc((size_t)NN * 128 * 2);
    unsigned short* W1p    = (unsigned short*)alloc((size_t)8 * 8 * 64 * 8 * 2);    // 64KB
    unsigned short* W2p    = (unsigned short*)alloc((size_t)16 * 8 * 64 * 8 * 2);   // 128KB

    hipMemsetAsync(bcnt, 0, (size_t)NB * 4, stream);
    prep_kernel<<<BS_BLOCKS + CAST_BLOCKS + PACK_BLOCKS, 256, 0, stream>>>(
        src, dst, bcnt, ebuf, x, x_bf, W1l, W1r, W1p, W2l, W2r, W2p);
    csr_kernel<<<NB, 256, 0, stream>>>(bcnt, ebuf, rowptr, col);

    // layer 1
    aggregate_bf_kernel<<<4 * 12500, 256, 0, stream>>>(rowptr, col, (const uint4*)x_bf,
                                                       (uint4*)agg_bf);
    gemm_mfma_kernel<128, false><<<(NN + 63) / 64, 256, 0, stream>>>(agg_bf, x_bf, W1p, b1,
                                                                     h1_bf, NN);
    // layer 2
    aggregate_bf_kernel<<<4 * 12500, 256, 0, stream>>>(rowptr, col, (const uint4*)h1_bf,
                                                       (uint4*)agg_bf);
    gemm_mfma_kernel<256, true><<<(NN + 63) / 64, 256, 0, stream>>>(agg_bf, h1_bf, W2p, b2,
                                                                    out, NN);
}

// Round 10
// 256.097 us; speedup vs baseline: 1.3620x; 1.2956x over previous
//
#include <hip/hip_runtime.h>

#define NN 50000
#define NE 800000
#define NB 782    // ceil(NN/64) buckets of 64 dst-nodes
#define CAP 1536  // per-bucket edge capacity (avg 1023, sigma 32 -> +16 sigma)

// ---------------- bf16 helpers (bits-level, RNE) ----------------

__device__ __forceinline__ unsigned short f2bf(float f) {
    union { float f; unsigned u; } v; v.f = f;
    unsigned u = v.u;
    return (unsigned short)((u + 0x7fffu + ((u >> 16) & 1u)) >> 16);
}
__device__ __forceinline__ float bfu_lo(unsigned p) {
    union { unsigned u; float f; } v; v.u = p << 16; return v.f;
}
__device__ __forceinline__ float bfu_hi(unsigned p) {
    union { unsigned u; float f; } v; v.u = p & 0xffff0000u; return v.f;
}

typedef __bf16 bf16x8 __attribute__((ext_vector_type(8)));
typedef float f32x4 __attribute__((ext_vector_type(4)));
union U16 { uint4 u; bf16x8 v; };

// ---------------- prep: binscatter + x->bf16 cast + W pack, one launch -------------------

#define BS_BLOCKS ((NE + 8191) / 8192)              // 98
#define CAST_BLOCKS ((NN * 128 / 4 + 255) / 256)    // 6250
#define PACK_BLOCKS ((24 * 8 * 64) / 256)           // 48

__device__ void binscatter_job(const int* __restrict__ src, const int* __restrict__ dst,
                               int* __restrict__ bcnt, unsigned* __restrict__ ebuf, int blk) {
    __shared__ int hist[NB];
    __shared__ int base[NB];
    const int BE = 8192;
    int tid = threadIdx.x;
    int e0 = blk * BE;
    for (int i = tid; i < NB; i += 256) hist[i] = 0;
    __syncthreads();
    for (int i = tid; i < BE; i += 256) {
        int e = e0 + i;
        if (e < NE) atomicAdd(&hist[dst[e] >> 6], 1);
    }
    __syncthreads();
    for (int i = tid; i < NB; i += 256) {
        int c = hist[i];
        base[i] = c ? atomicAdd(&bcnt[i], c) : 0;  // reserve contiguous run
        hist[i] = 0;                                // reuse as cursor
    }
    __syncthreads();
    for (int i = tid; i < BE; i += 256) {
        int e = e0 + i;
        if (e < NE) {
            int d = dst[e], b = d >> 6;
            int slot = base[b] + atomicAdd(&hist[b], 1);
            if (slot < CAP)
                ebuf[(size_t)b * CAP + slot] = (unsigned)src[e] | ((unsigned)(d & 63) << 16);
        }
    }
}

template <int N>
__device__ __forceinline__ void pack_one(const float* __restrict__ Wl,
                                         const float* __restrict__ Wr,
                                         unsigned short* __restrict__ Wp, int t) {
    // chunk c = nt*8+ks; lane holds B[k=ks*32+(lane>>4)*8+j][n=nt*16+(lane&15)], j=0..7
    int lane = t & 63, c = t >> 6;
    int ks = c & 7, nt = c >> 3;
    int n = nt * 16 + (lane & 15);
    int kq = ks * 32 + (lane >> 4) * 8;
    unsigned short tmp[8];
#pragma unroll
    for (int j = 0; j < 8; j++) {
        int k = kq + j;
        float w = (k < 128) ? Wl[(size_t)k * N + n] : Wr[(size_t)(k - 128) * N + n];
        tmp[j] = f2bf(w);
    }
    ((ushort4*)Wp)[(size_t)c * 128 + lane * 2 + 0] = make_ushort4(tmp[0], tmp[1], tmp[2], tmp[3]);
    ((ushort4*)Wp)[(size_t)c * 128 + lane * 2 + 1] = make_ushort4(tmp[4], tmp[5], tmp[6], tmp[7]);
}

__global__ __launch_bounds__(256) void prep_kernel(
    const int* __restrict__ src, const int* __restrict__ dst,
    int* __restrict__ bcnt, unsigned* __restrict__ ebuf,
    const float* __restrict__ x, unsigned short* __restrict__ x_bf,
    const float* __restrict__ W1l, const float* __restrict__ W1r, unsigned short* __restrict__ W1p,
    const float* __restrict__ W2l, const float* __restrict__ W2r, unsigned short* __restrict__ W2p) {
    int b = blockIdx.x;
    if (b < BS_BLOCKS) {
        binscatter_job(src, dst, bcnt, ebuf, b);
    } else if (b < BS_BLOCKS + CAST_BLOCKS) {
        int i = (b - BS_BLOCKS) * 256 + threadIdx.x;
        if (i < NN * 128 / 4) {
            float4 f = ((const float4*)x)[i];
            ((ushort4*)x_bf)[i] = make_ushort4(f2bf(f.x), f2bf(f.y), f2bf(f.z), f2bf(f.w));
        }
    } else {
        int t = (b - BS_BLOCKS - CAST_BLOCKS) * 256 + threadIdx.x;
        if (t < 8 * 8 * 64) pack_one<128>(W1l, W1r, W1p, t);
        else if (t < 24 * 8 * 64) pack_one<256>(W2l, W2r, W2p, t - 8 * 8 * 64);
    }
}

// ---------------- csr: one block per bucket (prefix over bcnt folded in) -------------------
// col stored as ushort (node ids < 65536): halves col traffic downstream.

__global__ __launch_bounds__(256) void csr_kernel(const int* __restrict__ bcnt,
                                                  const unsigned* __restrict__ ebuf,
                                                  int* __restrict__ rowptr,
                                                  unsigned short* __restrict__ col) {
    __shared__ int red[256];
    __shared__ int deg[64];
    __shared__ int cur[64];
    __shared__ int cbase_s;
    int b = blockIdx.x, tid = threadIdx.x;
    int s = 0;
    for (int i = tid; i < b; i += 256) s += bcnt[i];
    red[tid] = s;
    if (tid < 64) deg[tid] = 0;
    __syncthreads();
    for (int off = 128; off; off >>= 1) {
        if (tid < off) red[tid] += red[tid + off];
        __syncthreads();
    }
    if (tid == 0) cbase_s = red[0];
    __syncthreads();
    int cnt = bcnt[b], cbase = cbase_s;
    if (cnt > CAP) cnt = CAP;
    const unsigned* eb = ebuf + (size_t)b * CAP;
    for (int i = tid; i < cnt; i += 256) atomicAdd(&deg[(eb[i] >> 16) & 63], 1);
    __syncthreads();
    if (tid == 0) {
        int run = 0;
        for (int j = 0; j < 64; j++) { cur[j] = run; run += deg[j]; }
    }
    __syncthreads();
    int node = b * 64 + tid;
    if (tid < 64 && node < NN) rowptr[node] = cbase + cur[tid];
    if (b == NB - 1 && tid == 0) rowptr[NN] = NE;
    __syncthreads();
    for (int i = tid; i < cnt; i += 256) {
        unsigned e = eb[i];
        int pos = atomicAdd(&cur[(e >> 16) & 63], 1);
        col[cbase + pos] = (unsigned short)(e & 0xffffu);
    }
}

// ---------------- pull-based mean aggregation (R7-proven shape) ----------------------------
// one wave per node; lane-group g=lane>>4 targets neighbor i+g, each lane loads uint4 (16B):
// 4 x 256B rows in flight per load instruction. Cross-group combine via shfl_xor(16,32);
// lanes 0..15 write the 256B output row. 256B-contiguous-per-neighbor is the proven-fast
// access shape (R9's 64B chunking regressed 2.6x — do not split rows).

__global__ void aggregate_bf_kernel(const int* __restrict__ rowptr,
                                    const unsigned short* __restrict__ col,
                                    const uint4* __restrict__ feat4,  // [NN][16] 16B chunks
                                    uint4* __restrict__ out4) {
    int wid = (blockIdx.x * blockDim.x + threadIdx.x) >> 6;
    int lane = threadIdx.x & 63;
    if (wid >= NN) return;
    int beg = rowptr[wid], end = rowptr[wid + 1];
    int g = lane >> 4, c16 = lane & 15;
    float acc[8];
#pragma unroll
    for (int j = 0; j < 8; j++) acc[j] = 0.f;
    for (int i = beg; i < end; i += 4) {
        int idx = i + g;
        if (idx < end) {  // exec-masked tail: no wasted loads
            int s = col[idx];
            uint4 v = feat4[(size_t)s * 16 + c16];
            acc[0] += bfu_lo(v.x); acc[1] += bfu_hi(v.x);
            acc[2] += bfu_lo(v.y); acc[3] += bfu_hi(v.y);
            acc[4] += bfu_lo(v.z); acc[5] += bfu_hi(v.z);
            acc[6] += bfu_lo(v.w); acc[7] += bfu_hi(v.w);
        }
    }
#pragma unroll
    for (int j = 0; j < 8; j++) {
        acc[j] += __shfl_xor(acc[j], 16);
        acc[j] += __shfl_xor(acc[j], 32);
    }
    if (g == 0) {
        float inv = (end > beg) ? 1.0f / (float)(end - beg) : 0.0f;
        uint4 o;
        o.x = (unsigned)f2bf(acc[0] * inv) | ((unsigned)f2bf(acc[1] * inv) << 16);
        o.y = (unsigned)f2bf(acc[2] * inv) | ((unsigned)f2bf(acc[3] * inv) << 16);
        o.z = (unsigned)f2bf(acc[4] * inv) | ((unsigned)f2bf(acc[5] * inv) << 16);
        o.w = (unsigned)f2bf(acc[6] * inv) | ((unsigned)f2bf(acc[7] * inv) << 16);
        out4[(size_t)wid * 16 + c16] = o;
    }
}

// ---------------- MFMA GEMM + fused epilogue (no LDS, no barriers) — R7-proven -------------
// C[M,N] = [A0|A1](bf16) @ Wp + bias; sigmoid + row-L2 (+ log_softmax if FINAL).
// 256 thr = 4 waves; wave owns 16 rows x all N cols. A-frags: row-major 16B loads
// (A[m=lane&15][k=quad*8+j]); K=256 resident in 32 VGPRs. B-frags: 1KB coalesced chunks
// from L2-resident Wp. C/D: row=quad*4+reg, col=lane&15 -> shfl_xor width-16 reductions.

template <int N, bool FINAL>
__global__ __launch_bounds__(256) void gemm_mfma_kernel(
    const unsigned short* __restrict__ A0, const unsigned short* __restrict__ A1,
    const unsigned short* __restrict__ Wp, const float* __restrict__ bias,
    void* __restrict__ outp, int M) {
    const int NT = N / 16;
    int tid = threadIdx.x, wave = tid >> 6, lane = tid & 63;
    int quad = lane >> 4, col = lane & 15;
    int m_base = blockIdx.x * 64 + wave * 16;
    int row = m_base + col;
    int row_ld = row < M ? row : M - 1;

    bf16x8 a[8];
    const uint4* a0p = (const uint4*)(A0 + (size_t)row_ld * 128 + quad * 8);
    const uint4* a1p = (const uint4*)(A1 + (size_t)row_ld * 128 + quad * 8);
#pragma unroll
    for (int ks = 0; ks < 4; ks++) { U16 u; u.u = a0p[ks * 4]; a[ks] = u.v; }
#pragma unroll
    for (int ks = 0; ks < 4; ks++) { U16 u; u.u = a1p[ks * 4]; a[4 + ks] = u.v; }

    f32x4 acc[NT];
#pragma unroll
    for (int nt = 0; nt < NT; nt++) acc[nt] = (f32x4){0.f, 0.f, 0.f, 0.f};

    const uint4* wp = (const uint4*)Wp;  // chunk c: wp[c*64 + lane]
#pragma unroll
    for (int nt = 0; nt < NT; nt++) {
#pragma unroll
        for (int ks = 0; ks < 8; ks++) {
            U16 u; u.u = wp[(size_t)(nt * 8 + ks) * 64 + lane];
            acc[nt] = __builtin_amdgcn_mfma_f32_16x16x32_bf16(a[ks], u.v, acc[nt], 0, 0, 0);
        }
    }

    float ssq[4] = {0.f, 0.f, 0.f, 0.f};
#pragma unroll
    for (int nt = 0; nt < NT; nt++) {
        float bv = bias[nt * 16 + col];
#pragma unroll
        for (int r = 0; r < 4; r++) {
            float z = acc[nt][r] + bv;
            float s = 1.0f / (1.0f + __expf(-z));
            acc[nt][r] = s;
            ssq[r] += s * s;
        }
    }
#pragma unroll
    for (int r = 0; r < 4; r++) {
#pragma unroll
        for (int off = 1; off < 16; off <<= 1) ssq[r] += __shfl_xor(ssq[r], off, 16);
        float sc = 1.0f / fmaxf(sqrtf(ssq[r]), 1e-12f);
#pragma unroll
        for (int nt = 0; nt < NT; nt++) acc[nt][r] *= sc;
    }

    if (FINAL) {
#pragma unroll
        for (int r = 0; r < 4; r++) {
            float mx = -1e30f;
#pragma unroll
            for (int nt = 0; nt < NT; nt++) mx = fmaxf(mx, acc[nt][r]);
#pragma unroll
            for (int off = 1; off < 16; off <<= 1) mx = fmaxf(mx, __shfl_xor(mx, off, 16));
            float se = 0.f;
#pragma unroll
            for (int nt = 0; nt < NT; nt++) se += __expf(acc[nt][r] - mx);
#pragma unroll
            for (int off = 1; off < 16; off <<= 1) se += __shfl_xor(se, off, 16);
            float lse = mx + __logf(se);
#pragma unroll
            for (int nt = 0; nt < NT; nt++) acc[nt][r] -= lse;
        }
        float* op = (float*)outp;
#pragma unroll
        for (int r = 0; r < 4; r++) {
            int m = m_base + quad * 4 + r;
            if (m < M) {
#pragma unroll
                for (int nt = 0; nt < NT; nt++) op[(size_t)m * N + nt * 16 + col] = acc[nt][r];
            }
        }
    } else {
        unsigned short* op = (unsigned short*)outp;
#pragma unroll
        for (int r = 0; r < 4; r++) {
            int m = m_base + quad * 4 + r;
            if (m < M) {
#pragma unroll
                for (int nt = 0; nt < NT; nt++)
                    op[(size_t)m * N + nt * 16 + col] = f2bf(acc[nt][r]);
            }
        }
    }
}

// ---------------- launcher (5 graph nodes) ----------------

extern "C" void kernel_launch(void* const* d_in, const int* in_sizes, int n_in,
                              void* d_out, int out_size, void* d_ws, size_t ws_size,
                              hipStream_t stream) {
    const float* x   = (const float*)d_in[0];
    const int*   ei  = (const int*)d_in[1];
    const float* W1l = (const float*)d_in[2];
    const float* W1r = (const float*)d_in[3];
    const float* b1  = (const float*)d_in[4];
    const float* W2l = (const float*)d_in[5];
    const float* W2r = (const float*)d_in[6];
    const float* b2  = (const float*)d_in[7];
    float* out = (float*)d_out;

    const int* src = ei;
    const int* dst = ei + NE;

    char* ws = (char*)d_ws;
    size_t off = 0;
    auto alloc = [&](size_t bytes) -> void* {
        void* p = ws + off;
        off += (bytes + 255) / 256 * 256;
        return p;
    };
    int* rowptr           = (int*)alloc((size_t)(NN + 1) * 4);
    unsigned short* col   = (unsigned short*)alloc((size_t)NE * 2);
    int* bcnt             = (int*)alloc((size_t)NB * 4);
    unsigned* ebuf        = (unsigned*)alloc((size_t)NB * CAP * 4);  // 4.8MB
    unsigned short* x_bf   = (unsigned short*)alloc((size_t)NN * 128 * 2);
    unsigned short* agg_bf = (unsigned short*)alloc((size_t)NN * 128 * 2);
    unsigned short* h1_bf  = (unsigned short*)alloc((size_t)NN * 128 * 2);
    unsigned short* W1p    = (unsigned short*)alloc((size_t)8 * 8 * 64 * 8 * 2);    // 64KB
    unsigned short* W2p    = (unsigned short*)alloc((size_t)16 * 8 * 64 * 8 * 2);   // 128KB

    hipMemsetAsync(bcnt, 0, (size_t)NB * 4, stream);
    prep_kernel<<<BS_BLOCKS + CAST_BLOCKS + PACK_BLOCKS, 256, 0, stream>>>(
        src, dst, bcnt, ebuf, x, x_bf, W1l, W1r, W1p, W2l, W2r, W2p);
    csr_kernel<<<NB, 256, 0, stream>>>(bcnt, ebuf, rowptr, col);

    // layer 1
    aggregate_bf_kernel<<<(NN + 3) / 4, 256, 0, stream>>>(rowptr, col, (const uint4*)x_bf,
                                                          (uint4*)agg_bf);
    gemm_mfma_kernel<128, false><<<(NN + 63) / 64, 256, 0, stream>>>(agg_bf, x_bf, W1p, b1,
                                                                     h1_bf, NN);
    // layer 2
    aggregate_bf_kernel<<<(NN + 3) / 4, 256, 0, stream>>>(rowptr, col, (const uint4*)h1_bf,
                                                          (uint4*)agg_bf);
    gemm_mfma_kernel<256, true><<<(NN + 63) / 64, 256, 0, stream>>>(agg_bf, h1_bf, W2p, b2,
                                                                    out, NN);
}